// Round 10
// baseline (165.759 us; speedup 1.0000x reference)
//
#include <hip/hip_runtime.h>
#include <hip/hip_bf16.h>
#include <cstdint>

// Problem constants
#define B_    2
#define S_    2048
#define H_    512
#define N_    8
#define D_    64
#define BS_   4096      // B*S
#define CHUNK 64
#define NCH   32        // S_/CHUNK
#define NBN   16        // B*N
#define EPS_  1e-6f

typedef __attribute__((ext_vector_type(4))) float  f32x4;
typedef __attribute__((ext_vector_type(8))) short  short8;
typedef __attribute__((ext_vector_type(4))) short  short4_t;

static __device__ __forceinline__ unsigned short f2bf(float x) {
    __hip_bfloat16 h = __float2bfloat16(x);
    return *reinterpret_cast<unsigned short*>(&h);
}
static __device__ __forceinline__ float bf2f(unsigned short u) {
    unsigned int v = ((unsigned int)u) << 16;
    float f;
    __builtin_memcpy(&f, &v, 4);
    return f;
}

// ---------------------------------------------------------------------------
// K0b: weight transpose+convert: Wt[c][k] = bf16(W[k][c]).  grid (8,8,4)
// ---------------------------------------------------------------------------
__global__ __launch_bounds__(256) void convert_wt_kernel(
    const float* __restrict__ wq, const float* __restrict__ wk,
    const float* __restrict__ wv, const float* __restrict__ wo,
    unsigned short* __restrict__ wqt, unsigned short* __restrict__ wkt,
    unsigned short* __restrict__ wvt, unsigned short* __restrict__ wot)
{
    const int m = blockIdx.z;
    const float* W = (m == 0) ? wq : (m == 1) ? wk : (m == 2) ? wv : wo;
    unsigned short* Wt = (m == 0) ? wqt : (m == 1) ? wkt : (m == 2) ? wvt : wot;

    __shared__ float t[64][65];
    const int k0 = blockIdx.y * 64, c0 = blockIdx.x * 64;
    const int tid = threadIdx.x;
    const int rr = tid >> 6;
    const int cc = tid & 63;
#pragma unroll
    for (int p = 0; p < 16; p++) {
        int kl = rr + p * 4;
        t[kl][cc] = W[(size_t)(k0 + kl) * 512 + c0 + cc];
    }
    __syncthreads();
#pragma unroll
    for (int p = 0; p < 16; p++) {
        int cl = rr + p * 4;
        Wt[(size_t)(c0 + cl) * 512 + k0 + cc] = f2bf(t[cc][cl]);
    }
}

// ---------------------------------------------------------------------------
// MFMA GEMM body, 128x128 tile, BK=64, 256 thr (4 waves as 2x2 -> 64x64 each).
// MODE 0: phi, bf16 row-major out        (Q, f32 X)
// MODE 1: phi, bf16 row-major + [col][t] transposed out   (K, f32 X)
// MODE 2: no phi, transposed out only    (V, f32 X)
// ---------------------------------------------------------------------------
template<int MODE>
__device__ __forceinline__ void mfma_gemm_body(
    unsigned short (* __restrict__ As)[72], unsigned short (* __restrict__ Bs)[72],
    const void* __restrict__ Xv, const unsigned short* __restrict__ Wt,
    const float* __restrict__ bias,
    unsigned short* __restrict__ Obf, unsigned short* __restrict__ Ot)
{
    const int tid  = threadIdx.x;
    const int lane = tid & 63;
    const int w    = tid >> 6;
    const int wm   = (w & 1) * 64;
    const int wn   = (w >> 1) * 64;
    const int row0 = blockIdx.y * 128;
    const int col0 = blockIdx.x * 128;
    const int frow = lane & 15;
    const int fk   = (lane >> 4) * 8;

    f32x4 acc[4][4];
#pragma unroll
    for (int m = 0; m < 4; m++)
#pragma unroll
        for (int n = 0; n < 4; n++) acc[m][n] = (f32x4){0.f, 0.f, 0.f, 0.f};

    const int lr = tid >> 3;          // 0..31
    const int lc = (tid & 7) * 8;     // 0..56

    for (int k0 = 0; k0 < 512; k0 += 64) {
        // A tile 128x64 (f32 -> bf16 during staging)
#pragma unroll
        for (int p = 0; p < 4; p++) {
            int r = lr + p * 32;
            const float* X = (const float*)Xv;
            const float* src = X + (size_t)(row0 + r) * 512 + k0 + lc;
            float4 x0 = *reinterpret_cast<const float4*>(src);
            float4 x1 = *reinterpret_cast<const float4*>(src + 4);
            short8 o;
            o[0] = (short)f2bf(x0.x); o[1] = (short)f2bf(x0.y);
            o[2] = (short)f2bf(x0.z); o[3] = (short)f2bf(x0.w);
            o[4] = (short)f2bf(x1.x); o[5] = (short)f2bf(x1.y);
            o[6] = (short)f2bf(x1.z); o[7] = (short)f2bf(x1.w);
            *reinterpret_cast<short8*>(&As[r][lc]) = o;
        }
        // B tile 128x64
#pragma unroll
        for (int p = 0; p < 4; p++) {
            int r = (tid >> 3) + p * 32;
            *reinterpret_cast<short8*>(&Bs[r][lc]) =
                *reinterpret_cast<const short8*>(Wt + (size_t)(col0 + r) * 512 + k0 + lc);
        }
        __syncthreads();
#pragma unroll
        for (int kk = 0; kk < 64; kk += 32) {
            short8 a[4], b[4];
#pragma unroll
            for (int m = 0; m < 4; m++)
                a[m] = *reinterpret_cast<const short8*>(&As[wm + m * 16 + frow][kk + fk]);
#pragma unroll
            for (int n = 0; n < 4; n++)
                b[n] = *reinterpret_cast<const short8*>(&Bs[wn + n * 16 + frow][kk + fk]);
#pragma unroll
            for (int m = 0; m < 4; m++)
#pragma unroll
                for (int n = 0; n < 4; n++)
                    acc[m][n] = __builtin_amdgcn_mfma_f32_16x16x32_bf16(
                        a[m], b[n], acc[m][n], 0, 0, 0);
        }
        __syncthreads();
    }

    // Epilogue. C/D: col=lane&15, row=(lane>>4)*4+r (m89-verified)
#pragma unroll
    for (int n = 0; n < 4; n++) {
        int col = col0 + wn + n * 16 + frow;
        float bv_ = bias[col];
#pragma unroll
        for (int m = 0; m < 4; m++) {
            int rbase = row0 + wm + m * 16 + (lane >> 4) * 4;
            short4_t t4;
#pragma unroll
            for (int r = 0; r < 4; r++) {
                float val = acc[m][n][r] + bv_;
                if (MODE == 0 || MODE == 1)
                    val = (val > 0.f) ? (val + 1.f) : __expf(val);   // elu+1
                unsigned short ub = f2bf(val);
                t4[r] = (short)ub;
                if (MODE == 0 || MODE == 1)
                    Obf[(size_t)(rbase + r) * 512 + col] = ub;
            }
            if (MODE == 1 || MODE == 2) {
                int bb = rbase >> 11;          // batch
                int t_ = rbase & 2047;         // time within batch
                *reinterpret_cast<short4_t*>(
                    Ot + (size_t)bb * (512 * 2048) + (size_t)col * 2048 + t_) = t4;
            }
        }
    }
}

// K1: QKV projections from f32 inputs. grid (4, 32, 3), block 256, 128x128 tile
__global__ __launch_bounds__(256) void qkv_proj_kernel(
    const float* __restrict__ q_in, const float* __restrict__ k_in,
    const float* __restrict__ v_in,
    const unsigned short* __restrict__ wqt, const unsigned short* __restrict__ wkt,
    const unsigned short* __restrict__ wvt,
    const float* __restrict__ bq, const float* __restrict__ bk, const float* __restrict__ bv,
    unsigned short* __restrict__ pq, unsigned short* __restrict__ pk,
    unsigned short* __restrict__ pkT, unsigned short* __restrict__ pvT)
{
    __shared__ unsigned short As[128][72];
    __shared__ unsigned short Bs[128][72];
    int m = blockIdx.z;
    if (m == 0)      mfma_gemm_body<0>(As, Bs, q_in, wqt, bq, pq, nullptr);
    else if (m == 1) mfma_gemm_body<1>(As, Bs, k_in, wkt, bk, pk, pkT);
    else             mfma_gemm_body<2>(As, Bs, v_in, wvt, bv, nullptr, pvT);
}

// ---------------------------------------------------------------------------
// K23 (fused chunk-KV + exclusive scan):
//   M'_c[d][h] = sum_{t in chunk c} V[t,d]*K[t,h];  Mb = exclusive prefix (bf16)
//   z_c[h] = sum_t K[t,h];                          zb = exclusive prefix (f32)
// grid (16, 16): x = (dblk<<2)|hblk tile of 16x16, y = bn. block 256 (4 waves).
// ---------------------------------------------------------------------------
__global__ __launch_bounds__(256) void chunk_kvscan_kernel(
    const unsigned short* __restrict__ pkT, const unsigned short* __restrict__ pvT,
    unsigned short* __restrict__ Mb, float* __restrict__ zb)
{
    __shared__ float waveTot[4][256];     // per-wave state totals
    __shared__ float zTot[4][16];         // per-wave z totals

    const int tile = blockIdx.x;
    const int bn   = blockIdx.y;
    const int d0   = (tile >> 2) * 16;
    const int h0   = (tile & 3) * 16;
    const int b = bn >> 3, n = bn & 7;
    const int tid = threadIdx.x, lane = tid & 63, w = tid >> 6;
    const int frow = lane & 15, grp = lane >> 4, fk = grp * 8;
    const bool do_z = (tile >> 2) == 0;

    const size_t vrow = (size_t)b * (512 * 2048) + (size_t)(n * 64 + d0 + frow) * 2048;
    const size_t krow = (size_t)b * (512 * 2048) + (size_t)(n * 64 + h0 + frow) * 2048;

    f32x4 run = (f32x4){0.f, 0.f, 0.f, 0.f};
    f32x4 loc[8];
    float runz = 0.f, locz[8];

#pragma unroll
    for (int c = 0; c < 8; c++) {
        int t0 = (w * 8 + c) * 64;
        loc[c] = run;
        locz[c] = runz;
        short8 a0 = *reinterpret_cast<const short8*>(pvT + vrow + t0 + fk);
        short8 a1 = *reinterpret_cast<const short8*>(pvT + vrow + t0 + 32 + fk);
        short8 b0 = *reinterpret_cast<const short8*>(pkT + krow + t0 + fk);
        short8 b1 = *reinterpret_cast<const short8*>(pkT + krow + t0 + 32 + fk);
        run = __builtin_amdgcn_mfma_f32_16x16x32_bf16(a0, b0, run, 0, 0, 0);
        run = __builtin_amdgcn_mfma_f32_16x16x32_bf16(a1, b1, run, 0, 0, 0);
        if (do_z) {
            float zp = 0.f;
#pragma unroll
            for (int j = 0; j < 8; j++) zp += bf2f((unsigned short)b0[j]) + bf2f((unsigned short)b1[j]);
            zp += __shfl_xor(zp, 16);
            zp += __shfl_xor(zp, 32);
            runz += zp;
        }
    }

    // publish wave totals
#pragma unroll
    for (int r = 0; r < 4; r++)
        waveTot[w][(grp * 4 + r) * 16 + frow] = run[r];
    if (do_z && lane < 16) zTot[w][frow] = runz;
    __syncthreads();

    // carry = sum of totals of preceding waves
    f32x4 carry = (f32x4){0.f, 0.f, 0.f, 0.f};
    float carryz = 0.f;
    for (int pw = 0; pw < w; pw++) {
#pragma unroll
        for (int r = 0; r < 4; r++)
            carry[r] += waveTot[pw][(grp * 4 + r) * 16 + frow];
        carryz += zTot[pw][frow];
    }

    // store exclusive prefixes (state as bf16)
#pragma unroll
    for (int c = 0; c < 8; c++) {
        size_t mbase = ((size_t)bn * NCH + (w * 8 + c)) * 4096;
#pragma unroll
        for (int r = 0; r < 4; r++)
            Mb[mbase + (size_t)(d0 + grp * 4 + r) * 64 + h0 + frow] = f2bf(carry[r] + loc[c][r]);
        if (do_z && lane < 16)
            zb[((size_t)bn * NCH + (w * 8 + c)) * 64 + h0 + frow] = carryz + locz[c];
    }
}

// ---------------------------------------------------------------------------
// K4 (MFMA, fused with out-projection): per-chunk attention + final GEMM.
//   A = tril(Q K^T); O = A V + Q Sp'; denom = qz_prev + rowsum(A) + eps
//   av = O/denom, written SCRAMBLED into LDS: block (bn,c) produces exactly
//   8 complete rows [n*256+c*8 .. +8) of the out-proj input (8x512), so the
//   final out = av8 @ WoT + bo is computed in-block (B-frags streamed from
//   L2-resident wot).  Eliminates out_proj kernel + avb global buffer.
// grid (NCH, NBN), block 256 (4 waves)
// ---------------------------------------------------------------------------
__global__ __launch_bounds__(256) void chunk_attn_out_kernel(
    const unsigned short* __restrict__ pq, const unsigned short* __restrict__ pk,
    const unsigned short* __restrict__ pvT, const unsigned short* __restrict__ Mb,
    const float* __restrict__ zb, const unsigned short* __restrict__ wot,
    const float* __restrict__ bo, float* __restrict__ out)
{
    __shared__ unsigned short Qs[64][72], Ks[64][72];
    __shared__ unsigned short UN[9216];   // phase1: VT[64][72]+Ab[64][72]; phase2: av8[16][520]
    __shared__ float zs[64], dqz4[64][4], dAS[64];

    unsigned short (* __restrict__ VT)[72]  = (unsigned short(*)[72])UN;
    unsigned short (* __restrict__ Ab)[72]  = (unsigned short(*)[72])(UN + 4608);
    unsigned short (* __restrict__ av8)[520] = (unsigned short(*)[520])UN;

    const int c = blockIdx.x, bn = blockIdx.y;
    const int b = bn >> 3, n = bn & 7;
    const int row0 = b * S_ + c * 64;
    const int col0 = n * 64;
    const int t0 = c * 64;
    const size_t vbase = (size_t)b * 512 * 2048;
    const size_t mbase = ((size_t)bn * NCH + c) * 4096;
    const int tid = threadIdx.x, lane = tid & 63, w = tid >> 6;

    // stage (all bf16, straight short8 copies)
#pragma unroll
    for (int p = 0; p < 2; p++) {
        int r  = (tid >> 3) + p * 32;
        int c8 = (tid & 7) * 8;
        *reinterpret_cast<short8*>(&Qs[r][c8]) =
            *reinterpret_cast<const short8*>(pq + (size_t)(row0 + r) * 512 + col0 + c8);
        *reinterpret_cast<short8*>(&Ks[r][c8]) =
            *reinterpret_cast<const short8*>(pk + (size_t)(row0 + r) * 512 + col0 + c8);
        *reinterpret_cast<short8*>(&VT[r][c8]) =
            *reinterpret_cast<const short8*>(pvT + vbase + (size_t)(col0 + r) * 2048 + t0 + c8);
    }
    if (tid < 64) zs[tid] = zb[((size_t)bn * NCH + c) * 64 + tid];
    __syncthreads();

    const int frow = lane & 15, grp = lane >> 4, fk = grp * 8;
    const int srow = w * 16;

    // QK^T
    f32x4 a1[4];
#pragma unroll
    for (int tf = 0; tf < 4; tf++) a1[tf] = (f32x4){0.f, 0.f, 0.f, 0.f};
#pragma unroll
    for (int ks = 0; ks < 2; ks++) {
        short8 qa = *reinterpret_cast<const short8*>(&Qs[srow + frow][ks * 32 + fk]);
#pragma unroll
        for (int tf = 0; tf < 4; tf++) {
            short8 kb = *reinterpret_cast<const short8*>(&Ks[tf * 16 + frow][ks * 32 + fk]);
            a1[tf] = __builtin_amdgcn_mfma_f32_16x16x32_bf16(qa, kb, a1[tf], 0, 0, 0);
        }
    }

    // mask + rowsum + Ab
    float rs[4] = {0.f, 0.f, 0.f, 0.f};
#pragma unroll
    for (int tf = 0; tf < 4; tf++) {
        int t_ = tf * 16 + frow;
#pragma unroll
        for (int r = 0; r < 4; r++) {
            int s_ = srow + grp * 4 + r;
            float v = (t_ <= s_) ? a1[tf][r] : 0.f;
            rs[r] += v;
            Ab[s_][t_] = f2bf(v);
        }
    }
#pragma unroll
    for (int msk = 1; msk < 16; msk <<= 1)
#pragma unroll
        for (int r = 0; r < 4; r++) rs[r] += __shfl_xor(rs[r], msk);
    if (frow == 0) {
#pragma unroll
        for (int r = 0; r < 4; r++) dAS[srow + grp * 4 + r] = rs[r];
    }

    // q·z_prev, split across all 256 threads (16 MACs each)
    {
        int s = tid & 63, part = tid >> 6;
        float sdq = 0.f;
#pragma unroll
        for (int j = 0; j < 16; j++) {
            int h = part * 16 + j;
            sdq += bf2f(Qs[s][h]) * zs[h];
        }
        dqz4[s][part] = sdq;
    }
    __syncthreads();

    // O = A V + Q Sp'   (Sp' fragments direct from global Mb)
    f32x4 o[4];
#pragma unroll
    for (int df = 0; df < 4; df++) o[df] = (f32x4){0.f, 0.f, 0.f, 0.f};
#pragma unroll
    for (int ks = 0; ks < 2; ks++) {
        short8 aa = *reinterpret_cast<const short8*>(&Ab[srow + frow][ks * 32 + fk]);
        short8 qa = *reinterpret_cast<const short8*>(&Qs[srow + frow][ks * 32 + fk]);
#pragma unroll
        for (int df = 0; df < 4; df++) {
            short8 vb = *reinterpret_cast<const short8*>(&VT[df * 16 + frow][ks * 32 + fk]);
            short8 sp = *reinterpret_cast<const short8*>(
                Mb + mbase + (size_t)(df * 16 + frow) * 64 + ks * 32 + fk);
            o[df] = __builtin_amdgcn_mfma_f32_16x16x32_bf16(aa, vb, o[df], 0, 0, 0);
            o[df] = __builtin_amdgcn_mfma_f32_16x16x32_bf16(qa, sp, o[df], 0, 0, 0);
        }
    }

    // denominators
    float inv[4];
#pragma unroll
    for (int r = 0; r < 4; r++) {
        int s_loc = srow + grp * 4 + r;
        float dq = dqz4[s_loc][0] + dqz4[s_loc][1] + dqz4[s_loc][2] + dqz4[s_loc][3];
        inv[r] = 1.f / (dq + dAS[s_loc] + EPS_);
    }

    __syncthreads();   // everyone done reading VT/Ab -> UN becomes av8

    // scrambled write into LDS av8: row = s_loc>>3 (0..7), col = (s_loc&7)*64 + d
#pragma unroll
    for (int df = 0; df < 4; df++) {
        int d = df * 16 + frow;
#pragma unroll
        for (int r = 0; r < 4; r++) {
            int s_loc = srow + grp * 4 + r;
            av8[s_loc >> 3][(s_loc & 7) * 64 + d] = f2bf(o[df][r] * inv[r]);
        }
    }
    __syncthreads();

    // out-projection: out[8x512] = av8(8 valid of 16 rows) @ wot^T + bo
    // wave w owns cols [w*128, w*128+128): 8 n-frags of 16.
    f32x4 oacc[8];
#pragma unroll
    for (int nf = 0; nf < 8; nf++) oacc[nf] = (f32x4){0.f, 0.f, 0.f, 0.f};
    for (int ks2 = 0; ks2 < 16; ks2++) {
        int j0 = ks2 * 32;
        short8 a = *reinterpret_cast<const short8*>(&av8[frow][j0 + fk]);
#pragma unroll
        for (int nf = 0; nf < 8; nf++) {
            int h = w * 128 + nf * 16 + frow;
            short8 bfr = *reinterpret_cast<const short8*>(wot + (size_t)h * 512 + j0 + fk);
            oacc[nf] = __builtin_amdgcn_mfma_f32_16x16x32_bf16(a, bfr, oacc[nf], 0, 0, 0);
        }
    }
    // store rows 0..7 (C rows = grp*4+r; only grp<2 hold valid rows)
    const int orow0 = b * S_ + n * 256 + c * 8;
    if (grp < 2) {
#pragma unroll
        for (int nf = 0; nf < 8; nf++) {
            int h = w * 128 + nf * 16 + frow;
            float bb_ = bo[h];
#pragma unroll
            for (int r = 0; r < 4; r++) {
                int row = grp * 4 + r;
                out[(size_t)(orow0 + row) * 512 + h] = oacc[nf][r] + bb_;
            }
        }
    }
}

// ---------------------------------------------------------------------------
extern "C" void kernel_launch(void* const* d_in, const int* in_sizes, int n_in,
                              void* d_out, int out_size, void* d_ws, size_t ws_size,
                              hipStream_t stream)
{
    const float* q_in = (const float*)d_in[0];
    const float* k_in = (const float*)d_in[1];
    const float* v_in = (const float*)d_in[2];
    const float* wq   = (const float*)d_in[3];
    const float* bq   = (const float*)d_in[4];
    const float* wk   = (const float*)d_in[5];
    const float* bk   = (const float*)d_in[6];
    const float* wv   = (const float*)d_in[7];
    const float* bv   = (const float*)d_in[8];
    const float* wo   = (const float*)d_in[9];
    const float* bo   = (const float*)d_in[10];
    float* out = (float*)d_out;

    const size_t PLANE = (size_t)BS_ * 512;   // 2,097,152 elems

    float* ws = (float*)d_ws;
    float* zbuf = ws;                         // 32768 f32
    unsigned short* u16 = (unsigned short*)(zbuf + 32768);
    unsigned short* Mb  = u16;                // PLANE bf16
    unsigned short* pq  = Mb  + PLANE;        // PLANE each
    unsigned short* pk  = pq  + PLANE;
    unsigned short* pkT = pk  + PLANE;
    unsigned short* pvT = pkT + PLANE;
    unsigned short* wqt = pvT + PLANE;        // 262144 each
    unsigned short* wkt = wqt + 262144;
    unsigned short* wvt = wkt + 262144;
    unsigned short* wot = wvt + 262144;

    convert_wt_kernel<<<dim3(8, 8, 4), 256, 0, stream>>>(wq, wk, wv, wo, wqt, wkt, wvt, wot);
    qkv_proj_kernel<<<dim3(4, 32, 3), 256, 0, stream>>>(
        q_in, k_in, v_in, wqt, wkt, wvt, bq, bk, bv, pq, pk, pkT, pvT);
    chunk_kvscan_kernel<<<dim3(16, NBN), 256, 0, stream>>>(pkT, pvT, Mb, zbuf);
    chunk_attn_out_kernel<<<dim3(NCH, NBN), 256, 0, stream>>>(
        pq, pk, pvT, Mb, zbuf, wot, bo, out);
}

// Round 11
// 140.620 us; speedup vs baseline: 1.1788x; 1.1788x over previous
//
#include <hip/hip_runtime.h>
#include <hip/hip_bf16.h>
#include <cstdint>

// Problem constants
#define B_    2
#define S_    2048
#define H_    512
#define N_    8
#define D_    64
#define BS_   4096      // B*S
#define CHUNK 64
#define NCH   32        // S_/CHUNK
#define NBN   16        // B*N
#define EPS_  1e-6f

typedef __attribute__((ext_vector_type(4))) float  f32x4;
typedef __attribute__((ext_vector_type(8))) short  short8;
typedef __attribute__((ext_vector_type(4))) short  short4_t;

static __device__ __forceinline__ unsigned short f2bf(float x) {
    __hip_bfloat16 h = __float2bfloat16(x);
    return *reinterpret_cast<unsigned short*>(&h);
}
static __device__ __forceinline__ float bf2f(unsigned short u) {
    unsigned int v = ((unsigned int)u) << 16;
    float f;
    __builtin_memcpy(&f, &v, 4);
    return f;
}

// ---------------------------------------------------------------------------
// K0b: weight transpose+convert: Wt[c][k] = bf16(W[k][c]).  grid (8,8,4)
// ---------------------------------------------------------------------------
__global__ __launch_bounds__(256) void convert_wt_kernel(
    const float* __restrict__ wq, const float* __restrict__ wk,
    const float* __restrict__ wv, const float* __restrict__ wo,
    unsigned short* __restrict__ wqt, unsigned short* __restrict__ wkt,
    unsigned short* __restrict__ wvt, unsigned short* __restrict__ wot)
{
    const int m = blockIdx.z;
    const float* W = (m == 0) ? wq : (m == 1) ? wk : (m == 2) ? wv : wo;
    unsigned short* Wt = (m == 0) ? wqt : (m == 1) ? wkt : (m == 2) ? wvt : wot;

    __shared__ float t[64][65];
    const int k0 = blockIdx.y * 64, c0 = blockIdx.x * 64;
    const int tid = threadIdx.x;
    const int rr = tid >> 6;
    const int cc = tid & 63;
#pragma unroll
    for (int p = 0; p < 16; p++) {
        int kl = rr + p * 4;
        t[kl][cc] = W[(size_t)(k0 + kl) * 512 + c0 + cc];
    }
    __syncthreads();
#pragma unroll
    for (int p = 0; p < 16; p++) {
        int cl = rr + p * 4;
        Wt[(size_t)(c0 + cl) * 512 + k0 + cc] = f2bf(t[cc][cl]);
    }
}

// ---------------------------------------------------------------------------
// MFMA GEMM body, 128xBN tile, BK=64, 256 thr (4 waves as 2x2).
// row0/col0 passed in by the wrapper (XCD-aware grid mapping).
// MODE 0: phi, bf16 row-major out        (Q, f32 X)
// MODE 1: phi, bf16 row-major + [col][t] transposed out   (K, f32 X)
// MODE 2: no phi, transposed out only    (V, f32 X)
// MODE 3: no phi, f32 row-major out      (out-proj, bf16 X)
// ---------------------------------------------------------------------------
template<int MODE, int BN>
__device__ __forceinline__ void mfma_gemm_body(
    unsigned short (* __restrict__ As)[72], unsigned short (* __restrict__ Bs)[72],
    const void* __restrict__ Xv, const unsigned short* __restrict__ Wt,
    const float* __restrict__ bias,
    unsigned short* __restrict__ Obf, unsigned short* __restrict__ Ot,
    float* __restrict__ Of, int row0, int col0)
{
    constexpr int NF = BN / 32;       // col frags per wave (4 or 2)
    const int tid  = threadIdx.x;
    const int lane = tid & 63;
    const int w    = tid >> 6;
    const int wm   = (w & 1) * 64;
    const int wn   = (w >> 1) * (BN / 2);
    const int frow = lane & 15;
    const int fk   = (lane >> 4) * 8;

    f32x4 acc[4][NF];
#pragma unroll
    for (int m = 0; m < 4; m++)
#pragma unroll
        for (int n = 0; n < NF; n++) acc[m][n] = (f32x4){0.f, 0.f, 0.f, 0.f};

    const int lr = tid >> 3;          // 0..31
    const int lc = (tid & 7) * 8;     // 0..56

    for (int k0 = 0; k0 < 512; k0 += 64) {
        // A tile 128x64
#pragma unroll
        for (int p = 0; p < 4; p++) {
            int r = lr + p * 32;
            if (MODE == 3) {
                const unsigned short* X = (const unsigned short*)Xv;
                *reinterpret_cast<short8*>(&As[r][lc]) =
                    *reinterpret_cast<const short8*>(X + (size_t)(row0 + r) * 512 + k0 + lc);
            } else {
                const float* X = (const float*)Xv;
                const float* src = X + (size_t)(row0 + r) * 512 + k0 + lc;
                float4 x0 = *reinterpret_cast<const float4*>(src);
                float4 x1 = *reinterpret_cast<const float4*>(src + 4);
                short8 o;
                o[0] = (short)f2bf(x0.x); o[1] = (short)f2bf(x0.y);
                o[2] = (short)f2bf(x0.z); o[3] = (short)f2bf(x0.w);
                o[4] = (short)f2bf(x1.x); o[5] = (short)f2bf(x1.y);
                o[6] = (short)f2bf(x1.z); o[7] = (short)f2bf(x1.w);
                *reinterpret_cast<short8*>(&As[r][lc]) = o;
            }
        }
        // B tile BNx64
#pragma unroll
        for (int p = 0; p < BN / 32; p++) {
            int r = (tid >> 3) + p * 32;
            *reinterpret_cast<short8*>(&Bs[r][lc]) =
                *reinterpret_cast<const short8*>(Wt + (size_t)(col0 + r) * 512 + k0 + lc);
        }
        __syncthreads();
#pragma unroll
        for (int kk = 0; kk < 64; kk += 32) {
            short8 a[4], b[NF];
#pragma unroll
            for (int m = 0; m < 4; m++)
                a[m] = *reinterpret_cast<const short8*>(&As[wm + m * 16 + frow][kk + fk]);
#pragma unroll
            for (int n = 0; n < NF; n++)
                b[n] = *reinterpret_cast<const short8*>(&Bs[wn + n * 16 + frow][kk + fk]);
#pragma unroll
            for (int m = 0; m < 4; m++)
#pragma unroll
                for (int n = 0; n < NF; n++)
                    acc[m][n] = __builtin_amdgcn_mfma_f32_16x16x32_bf16(
                        a[m], b[n], acc[m][n], 0, 0, 0);
        }
        __syncthreads();
    }

    // Epilogue. C/D: col=lane&15, row=(lane>>4)*4+r (m89-verified)
#pragma unroll
    for (int n = 0; n < NF; n++) {
        int col = col0 + wn + n * 16 + frow;
        float bv_ = bias[col];
#pragma unroll
        for (int m = 0; m < 4; m++) {
            int rbase = row0 + wm + m * 16 + (lane >> 4) * 4;
            short4_t t4;
#pragma unroll
            for (int r = 0; r < 4; r++) {
                float val = acc[m][n][r] + bv_;
                if (MODE == 0 || MODE == 1)
                    val = (val > 0.f) ? (val + 1.f) : __expf(val);   // elu+1
                if (MODE == 3) {
                    Of[(size_t)(rbase + r) * 512 + col] = val;
                } else {
                    unsigned short ub = f2bf(val);
                    t4[r] = (short)ub;
                    if (MODE == 0 || MODE == 1)
                        Obf[(size_t)(rbase + r) * 512 + col] = ub;
                }
            }
            if (MODE == 1 || MODE == 2) {
                int bb = rbase >> 11;          // batch
                int t_ = rbase & 2047;         // time within batch
                *reinterpret_cast<short4_t*>(
                    Ot + (size_t)bb * (512 * 2048) + (size_t)col * 2048 + t_) = t4;
            }
        }
    }
}

// K1: QKV projections from f32 inputs. grid (32, 4, 3): x = ROW panel (fastest)
// so the 4 col-blocks sharing an A panel are strided 32 apart -> same XCD ->
// A re-reads served by that XCD's L2 instead of HBM.
__global__ __launch_bounds__(256) void qkv_proj_kernel(
    const float* __restrict__ q_in, const float* __restrict__ k_in,
    const float* __restrict__ v_in,
    const unsigned short* __restrict__ wqt, const unsigned short* __restrict__ wkt,
    const unsigned short* __restrict__ wvt,
    const float* __restrict__ bq, const float* __restrict__ bk, const float* __restrict__ bv,
    unsigned short* __restrict__ pq, unsigned short* __restrict__ pk,
    unsigned short* __restrict__ pkT, unsigned short* __restrict__ pvT)
{
    __shared__ unsigned short As[128][72];
    __shared__ unsigned short Bs[128][72];
    const int row0 = blockIdx.x * 128;
    const int col0 = blockIdx.y * 128;
    int m = blockIdx.z;
    if (m == 0)      mfma_gemm_body<0, 128>(As, Bs, q_in, wqt, bq, pq, nullptr, nullptr, row0, col0);
    else if (m == 1) mfma_gemm_body<1, 128>(As, Bs, k_in, wkt, bk, pk, pkT, nullptr, row0, col0);
    else             mfma_gemm_body<2, 128>(As, Bs, v_in, wvt, bv, nullptr, pvT, nullptr, row0, col0);
}

// K5: output projection. grid (32, 8): x = ROW panel (same XCD trick)
__global__ __launch_bounds__(256) void out_proj_kernel(
    const unsigned short* __restrict__ avb, const unsigned short* __restrict__ wot,
    const float* __restrict__ bo, float* __restrict__ out)
{
    __shared__ unsigned short As[128][72];
    __shared__ unsigned short Bs[64][72];
    const int row0 = blockIdx.x * 128;
    const int col0 = blockIdx.y * 64;
    mfma_gemm_body<3, 64>(As, Bs, avb, wot, bo, nullptr, nullptr, out, row0, col0);
}

// ---------------------------------------------------------------------------
// K23 (fused chunk-KV + exclusive scan):
//   M'_c[d][h] = sum_{t in chunk c} V[t,d]*K[t,h];  Mb = exclusive prefix (bf16)
//   z_c[h] = sum_t K[t,h];                          zb = exclusive prefix (f32)
// grid (16, 16): x = (dblk<<2)|hblk tile of 16x16, y = bn. block 256 (4 waves).
// ---------------------------------------------------------------------------
__global__ __launch_bounds__(256) void chunk_kvscan_kernel(
    const unsigned short* __restrict__ pkT, const unsigned short* __restrict__ pvT,
    unsigned short* __restrict__ Mb, float* __restrict__ zb)
{
    __shared__ float waveTot[4][256];     // per-wave state totals
    __shared__ float zTot[4][16];         // per-wave z totals

    const int tile = blockIdx.x;
    const int bn   = blockIdx.y;
    const int d0   = (tile >> 2) * 16;
    const int h0   = (tile & 3) * 16;
    const int b = bn >> 3, n = bn & 7;
    const int tid = threadIdx.x, lane = tid & 63, w = tid >> 6;
    const int frow = lane & 15, grp = lane >> 4, fk = grp * 8;
    const bool do_z = (tile >> 2) == 0;

    const size_t vrow = (size_t)b * (512 * 2048) + (size_t)(n * 64 + d0 + frow) * 2048;
    const size_t krow = (size_t)b * (512 * 2048) + (size_t)(n * 64 + h0 + frow) * 2048;

    f32x4 run = (f32x4){0.f, 0.f, 0.f, 0.f};
    f32x4 loc[8];
    float runz = 0.f, locz[8];

#pragma unroll
    for (int c = 0; c < 8; c++) {
        int t0 = (w * 8 + c) * 64;
        loc[c] = run;
        locz[c] = runz;
        short8 a0 = *reinterpret_cast<const short8*>(pvT + vrow + t0 + fk);
        short8 a1 = *reinterpret_cast<const short8*>(pvT + vrow + t0 + 32 + fk);
        short8 b0 = *reinterpret_cast<const short8*>(pkT + krow + t0 + fk);
        short8 b1 = *reinterpret_cast<const short8*>(pkT + krow + t0 + 32 + fk);
        run = __builtin_amdgcn_mfma_f32_16x16x32_bf16(a0, b0, run, 0, 0, 0);
        run = __builtin_amdgcn_mfma_f32_16x16x32_bf16(a1, b1, run, 0, 0, 0);
        if (do_z) {
            float zp = 0.f;
#pragma unroll
            for (int j = 0; j < 8; j++) zp += bf2f((unsigned short)b0[j]) + bf2f((unsigned short)b1[j]);
            zp += __shfl_xor(zp, 16);
            zp += __shfl_xor(zp, 32);
            runz += zp;
        }
    }

    // publish wave totals
#pragma unroll
    for (int r = 0; r < 4; r++)
        waveTot[w][(grp * 4 + r) * 16 + frow] = run[r];
    if (do_z && lane < 16) zTot[w][frow] = runz;
    __syncthreads();

    // carry = sum of totals of preceding waves
    f32x4 carry = (f32x4){0.f, 0.f, 0.f, 0.f};
    float carryz = 0.f;
    for (int pw = 0; pw < w; pw++) {
#pragma unroll
        for (int r = 0; r < 4; r++)
            carry[r] += waveTot[pw][(grp * 4 + r) * 16 + frow];
        carryz += zTot[pw][frow];
    }

    // store exclusive prefixes (state as bf16)
#pragma unroll
    for (int c = 0; c < 8; c++) {
        size_t mbase = ((size_t)bn * NCH + (w * 8 + c)) * 4096;
#pragma unroll
        for (int r = 0; r < 4; r++)
            Mb[mbase + (size_t)(d0 + grp * 4 + r) * 64 + h0 + frow] = f2bf(carry[r] + loc[c][r]);
        if (do_z && lane < 16)
            zb[((size_t)bn * NCH + (w * 8 + c)) * 64 + h0 + frow] = carryz + locz[c];
    }
}

// ---------------------------------------------------------------------------
// K4 (MFMA): per-chunk attention.
//   A = tril(Q K^T); O = A V + Q Sp'; denom = qz_prev + rowsum(A) + eps
//   Sp' fragments read directly from global Mb (L2-hot).
// grid (NCH, NBN), block 256 (4 waves; wave w owns rows w*16..w*16+15)
// ---------------------------------------------------------------------------
__global__ __launch_bounds__(256) void chunk_attn_kernel(
    const unsigned short* __restrict__ pq, const unsigned short* __restrict__ pk,
    const unsigned short* __restrict__ pvT, const unsigned short* __restrict__ Mb,
    const float* __restrict__ zb, unsigned short* __restrict__ av)
{
    __shared__ unsigned short Qs[64][72], Ks[64][72], VT[64][72], Ab[64][72];
    __shared__ float zs[64], dqz4[64][4], dAS[64];

    const int c = blockIdx.x, bn = blockIdx.y;
    const int b = bn >> 3, n = bn & 7;
    const int row0 = b * S_ + c * 64;
    const int col0 = n * 64;
    const int t0 = c * 64;
    const size_t vbase = (size_t)b * 512 * 2048;
    const size_t mbase = ((size_t)bn * NCH + c) * 4096;
    const int tid = threadIdx.x, lane = tid & 63, w = tid >> 6;

    // stage (all bf16, straight short8 copies)
#pragma unroll
    for (int p = 0; p < 2; p++) {
        int r  = (tid >> 3) + p * 32;
        int c8 = (tid & 7) * 8;
        *reinterpret_cast<short8*>(&Qs[r][c8]) =
            *reinterpret_cast<const short8*>(pq + (size_t)(row0 + r) * 512 + col0 + c8);
        *reinterpret_cast<short8*>(&Ks[r][c8]) =
            *reinterpret_cast<const short8*>(pk + (size_t)(row0 + r) * 512 + col0 + c8);
        *reinterpret_cast<short8*>(&VT[r][c8]) =
            *reinterpret_cast<const short8*>(pvT + vbase + (size_t)(col0 + r) * 2048 + t0 + c8);
    }
    if (tid < 64) zs[tid] = zb[((size_t)bn * NCH + c) * 64 + tid];
    __syncthreads();

    const int frow = lane & 15, grp = lane >> 4, fk = grp * 8;
    const int srow = w * 16;

    // QK^T
    f32x4 a1[4];
#pragma unroll
    for (int tf = 0; tf < 4; tf++) a1[tf] = (f32x4){0.f, 0.f, 0.f, 0.f};
#pragma unroll
    for (int ks = 0; ks < 2; ks++) {
        short8 qa = *reinterpret_cast<const short8*>(&Qs[srow + frow][ks * 32 + fk]);
#pragma unroll
        for (int tf = 0; tf < 4; tf++) {
            short8 kb = *reinterpret_cast<const short8*>(&Ks[tf * 16 + frow][ks * 32 + fk]);
            a1[tf] = __builtin_amdgcn_mfma_f32_16x16x32_bf16(qa, kb, a1[tf], 0, 0, 0);
        }
    }

    // mask + rowsum + Ab
    float rs[4] = {0.f, 0.f, 0.f, 0.f};
#pragma unroll
    for (int tf = 0; tf < 4; tf++) {
        int t_ = tf * 16 + frow;
#pragma unroll
        for (int r = 0; r < 4; r++) {
            int s_ = srow + grp * 4 + r;
            float v = (t_ <= s_) ? a1[tf][r] : 0.f;
            rs[r] += v;
            Ab[s_][t_] = f2bf(v);
        }
    }
#pragma unroll
    for (int msk = 1; msk < 16; msk <<= 1)
#pragma unroll
        for (int r = 0; r < 4; r++) rs[r] += __shfl_xor(rs[r], msk);
    if (frow == 0) {
#pragma unroll
        for (int r = 0; r < 4; r++) dAS[srow + grp * 4 + r] = rs[r];
    }

    // q·z_prev, split across all 256 threads (16 MACs each)
    {
        int s = tid & 63, part = tid >> 6;
        float sdq = 0.f;
#pragma unroll
        for (int j = 0; j < 16; j++) {
            int h = part * 16 + j;
            sdq += bf2f(Qs[s][h]) * zs[h];
        }
        dqz4[s][part] = sdq;
    }
    __syncthreads();

    // O = A V + Q Sp'   (Sp' fragments direct from global Mb)
    f32x4 o[4];
#pragma unroll
    for (int df = 0; df < 4; df++) o[df] = (f32x4){0.f, 0.f, 0.f, 0.f};
#pragma unroll
    for (int ks = 0; ks < 2; ks++) {
        short8 aa = *reinterpret_cast<const short8*>(&Ab[srow + frow][ks * 32 + fk]);
        short8 qa = *reinterpret_cast<const short8*>(&Qs[srow + frow][ks * 32 + fk]);
#pragma unroll
        for (int df = 0; df < 4; df++) {
            short8 vb = *reinterpret_cast<const short8*>(&VT[df * 16 + frow][ks * 32 + fk]);
            short8 sp = *reinterpret_cast<const short8*>(
                Mb + mbase + (size_t)(df * 16 + frow) * 64 + ks * 32 + fk);
            o[df] = __builtin_amdgcn_mfma_f32_16x16x32_bf16(aa, vb, o[df], 0, 0, 0);
            o[df] = __builtin_amdgcn_mfma_f32_16x16x32_bf16(qa, sp, o[df], 0, 0, 0);
        }
    }

    // divide + scrambled bf16 store
    float inv[4];
    size_t obase[4];
#pragma unroll
    for (int r = 0; r < 4; r++) {
        int s_loc = srow + grp * 4 + r;
        float dq = dqz4[s_loc][0] + dqz4[s_loc][1] + dqz4[s_loc][2] + dqz4[s_loc][3];
        inv[r] = 1.f / (dq + dAS[s_loc] + EPS_);
        int s_b = c * 64 + s_loc;
        int jj  = n * S_ + s_b;
        obase[r] = (size_t)(b * S_ + (jj >> 3)) * 512 + (size_t)(jj & 7) * 64;
    }
#pragma unroll
    for (int df = 0; df < 4; df++) {
        int d = df * 16 + frow;
#pragma unroll
        for (int r = 0; r < 4; r++)
            av[obase[r] + d] = f2bf(o[df][r] * inv[r]);
    }
}

// ---------------------------------------------------------------------------
extern "C" void kernel_launch(void* const* d_in, const int* in_sizes, int n_in,
                              void* d_out, int out_size, void* d_ws, size_t ws_size,
                              hipStream_t stream)
{
    const float* q_in = (const float*)d_in[0];
    const float* k_in = (const float*)d_in[1];
    const float* v_in = (const float*)d_in[2];
    const float* wq   = (const float*)d_in[3];
    const float* bq   = (const float*)d_in[4];
    const float* wk   = (const float*)d_in[5];
    const float* bk   = (const float*)d_in[6];
    const float* wv   = (const float*)d_in[7];
    const float* bv   = (const float*)d_in[8];
    const float* wo   = (const float*)d_in[9];
    const float* bo   = (const float*)d_in[10];
    float* out = (float*)d_out;

    const size_t PLANE = (size_t)BS_ * 512;   // 2,097,152 elems

    float* ws = (float*)d_ws;
    float* zbuf = ws;                         // 32768 f32
    unsigned short* u16 = (unsigned short*)(zbuf + 32768);
    unsigned short* Mb  = u16;                // PLANE bf16
    unsigned short* pq  = Mb  + PLANE;        // PLANE each
    unsigned short* pk  = pq  + PLANE;
    unsigned short* pkT = pk  + PLANE;
    unsigned short* pvT = pkT + PLANE;
    unsigned short* avb = pvT + PLANE;
    unsigned short* wqt = avb + PLANE;        // 262144 each
    unsigned short* wkt = wqt + 262144;
    unsigned short* wvt = wkt + 262144;
    unsigned short* wot = wvt + 262144;

    convert_wt_kernel<<<dim3(8, 8, 4), 256, 0, stream>>>(wq, wk, wv, wo, wqt, wkt, wvt, wot);
    qkv_proj_kernel<<<dim3(32, 4, 3), 256, 0, stream>>>(
        q_in, k_in, v_in, wqt, wkt, wvt, bq, bk, bv, pq, pk, pkT, pvT);
    chunk_kvscan_kernel<<<dim3(16, NBN), 256, 0, stream>>>(pkT, pvT, Mb, zbuf);
    chunk_attn_kernel<<<dim3(NCH, NBN), 256, 0, stream>>>(pq, pk, pvT, Mb, zbuf, avb);
    out_proj_kernel<<<dim3(32, 8), 256, 0, stream>>>(avb, wot, bo, out);
}

// Round 13
// 140.612 us; speedup vs baseline: 1.1788x; 1.0001x over previous
//
#include <hip/hip_runtime.h>
#include <hip/hip_bf16.h>
#include <cstdint>

// Problem constants
#define B_    2
#define S_    2048
#define H_    512
#define N_    8
#define D_    64
#define BS_   4096      // B*S
#define CHUNK 64
#define NCH   32        // S_/CHUNK
#define NBN   16        // B*N
#define EPS_  1e-6f

typedef __attribute__((ext_vector_type(4))) float  f32x4;
typedef __attribute__((ext_vector_type(8))) short  short8;
typedef __attribute__((ext_vector_type(4))) short  short4_t;

static __device__ __forceinline__ unsigned short f2bf(float x) {
    __hip_bfloat16 h = __float2bfloat16(x);
    return *reinterpret_cast<unsigned short*>(&h);
}
static __device__ __forceinline__ float bf2f(unsigned short u) {
    unsigned int v = ((unsigned int)u) << 16;
    float f;
    __builtin_memcpy(&f, &v, 4);
    return f;
}

// ---------------------------------------------------------------------------
// K0b: weight transpose+convert: Wt[c][k] = bf16(W[k][c]).  grid (8,8,4)
// ---------------------------------------------------------------------------
__global__ __launch_bounds__(256) void convert_wt_kernel(
    const float* __restrict__ wq, const float* __restrict__ wk,
    const float* __restrict__ wv, const float* __restrict__ wo,
    unsigned short* __restrict__ wqt, unsigned short* __restrict__ wkt,
    unsigned short* __restrict__ wvt, unsigned short* __restrict__ wot)
{
    const int m = blockIdx.z;
    const float* W = (m == 0) ? wq : (m == 1) ? wk : (m == 2) ? wv : wo;
    unsigned short* Wt = (m == 0) ? wqt : (m == 1) ? wkt : (m == 2) ? wvt : wot;

    __shared__ float t[64][65];
    const int k0 = blockIdx.y * 64, c0 = blockIdx.x * 64;
    const int tid = threadIdx.x;
    const int rr = tid >> 6;
    const int cc = tid & 63;
#pragma unroll
    for (int p = 0; p < 16; p++) {
        int kl = rr + p * 4;
        t[kl][cc] = W[(size_t)(k0 + kl) * 512 + c0 + cc];
    }
    __syncthreads();
#pragma unroll
    for (int p = 0; p < 16; p++) {
        int cl = rr + p * 4;
        Wt[(size_t)(c0 + cl) * 512 + k0 + cc] = f2bf(t[cc][cl]);
    }
}

// ---------------------------------------------------------------------------
// MFMA GEMM body for QKV, 128x128 tile, BK=64, 256 thr (4 waves as 2x2).
// MODE 0: phi, bf16 row-major out        (Q, f32 X)
// MODE 1: phi, bf16 row-major + [col][t] transposed out   (K, f32 X)
// MODE 2: no phi, transposed out only    (V, f32 X)
// ---------------------------------------------------------------------------
template<int MODE>
__device__ __forceinline__ void mfma_gemm_body(
    unsigned short (* __restrict__ As)[72], unsigned short (* __restrict__ Bs)[72],
    const void* __restrict__ Xv, const unsigned short* __restrict__ Wt,
    const float* __restrict__ bias,
    unsigned short* __restrict__ Obf, unsigned short* __restrict__ Ot,
    int row0, int col0)
{
    const int tid  = threadIdx.x;
    const int lane = tid & 63;
    const int w    = tid >> 6;
    const int wm   = (w & 1) * 64;
    const int wn   = (w >> 1) * 64;
    const int frow = lane & 15;
    const int fk   = (lane >> 4) * 8;

    f32x4 acc[4][4];
#pragma unroll
    for (int m = 0; m < 4; m++)
#pragma unroll
        for (int n = 0; n < 4; n++) acc[m][n] = (f32x4){0.f, 0.f, 0.f, 0.f};

    const int lr = tid >> 3;          // 0..31
    const int lc = (tid & 7) * 8;     // 0..56

    for (int k0 = 0; k0 < 512; k0 += 64) {
        // A tile 128x64 (f32 -> bf16 during staging)
#pragma unroll
        for (int p = 0; p < 4; p++) {
            int r = lr + p * 32;
            const float* X = (const float*)Xv;
            const float* src = X + (size_t)(row0 + r) * 512 + k0 + lc;
            float4 x0 = *reinterpret_cast<const float4*>(src);
            float4 x1 = *reinterpret_cast<const float4*>(src + 4);
            short8 o;
            o[0] = (short)f2bf(x0.x); o[1] = (short)f2bf(x0.y);
            o[2] = (short)f2bf(x0.z); o[3] = (short)f2bf(x0.w);
            o[4] = (short)f2bf(x1.x); o[5] = (short)f2bf(x1.y);
            o[6] = (short)f2bf(x1.z); o[7] = (short)f2bf(x1.w);
            *reinterpret_cast<short8*>(&As[r][lc]) = o;
        }
        // B tile 128x64
#pragma unroll
        for (int p = 0; p < 4; p++) {
            int r = (tid >> 3) + p * 32;
            *reinterpret_cast<short8*>(&Bs[r][lc]) =
                *reinterpret_cast<const short8*>(Wt + (size_t)(col0 + r) * 512 + k0 + lc);
        }
        __syncthreads();
#pragma unroll
        for (int kk = 0; kk < 64; kk += 32) {
            short8 a[4], b[4];
#pragma unroll
            for (int m = 0; m < 4; m++)
                a[m] = *reinterpret_cast<const short8*>(&As[wm + m * 16 + frow][kk + fk]);
#pragma unroll
            for (int n = 0; n < 4; n++)
                b[n] = *reinterpret_cast<const short8*>(&Bs[wn + n * 16 + frow][kk + fk]);
#pragma unroll
            for (int m = 0; m < 4; m++)
#pragma unroll
                for (int n = 0; n < 4; n++)
                    acc[m][n] = __builtin_amdgcn_mfma_f32_16x16x32_bf16(
                        a[m], b[n], acc[m][n], 0, 0, 0);
        }
        __syncthreads();
    }

    // Epilogue. C/D: col=lane&15, row=(lane>>4)*4+r (m89-verified)
#pragma unroll
    for (int n = 0; n < 4; n++) {
        int col = col0 + wn + n * 16 + frow;
        float bv_ = bias[col];
#pragma unroll
        for (int m = 0; m < 4; m++) {
            int rbase = row0 + wm + m * 16 + (lane >> 4) * 4;
            short4_t t4;
#pragma unroll
            for (int r = 0; r < 4; r++) {
                float val = acc[m][n][r] + bv_;
                if (MODE == 0 || MODE == 1)
                    val = (val > 0.f) ? (val + 1.f) : __expf(val);   // elu+1
                unsigned short ub = f2bf(val);
                t4[r] = (short)ub;
                if (MODE == 0 || MODE == 1)
                    Obf[(size_t)(rbase + r) * 512 + col] = ub;
            }
            if (MODE == 1 || MODE == 2) {
                int bb = rbase >> 11;          // batch
                int t_ = rbase & 2047;         // time within batch
                *reinterpret_cast<short4_t*>(
                    Ot + (size_t)bb * (512 * 2048) + (size_t)col * 2048 + t_) = t4;
            }
        }
    }
}

// K1: QKV projections from f32 inputs. grid (32, 4, 3): x = ROW panel (fastest)
// -> the 4 col-blocks sharing an A panel land on the same XCD (stride 32 % 8 == 0).
__global__ __launch_bounds__(256) void qkv_proj_kernel(
    const float* __restrict__ q_in, const float* __restrict__ k_in,
    const float* __restrict__ v_in,
    const unsigned short* __restrict__ wqt, const unsigned short* __restrict__ wkt,
    const unsigned short* __restrict__ wvt,
    const float* __restrict__ bq, const float* __restrict__ bk, const float* __restrict__ bv,
    unsigned short* __restrict__ pq, unsigned short* __restrict__ pk,
    unsigned short* __restrict__ pkT, unsigned short* __restrict__ pvT)
{
    __shared__ unsigned short As[128][72];
    __shared__ unsigned short Bs[128][72];
    const int row0 = blockIdx.x * 128;
    const int col0 = blockIdx.y * 128;
    int m = blockIdx.z;
    if (m == 0)      mfma_gemm_body<0>(As, Bs, q_in, wqt, bq, pq, nullptr, row0, col0);
    else if (m == 1) mfma_gemm_body<1>(As, Bs, k_in, wkt, bk, pk, pkT, row0, col0);
    else             mfma_gemm_body<2>(As, Bs, v_in, wvt, bv, nullptr, pvT, row0, col0);
}

// ---------------------------------------------------------------------------
// K5: output projection, 64x64 tile, BK=64, grid (64, 8), 256 thr (2x2 waves,
// 32x32 per wave).  Light VGPR/LDS -> high occupancy for latency hiding.
// ---------------------------------------------------------------------------
__global__ __launch_bounds__(256) void out_proj_kernel(
    const unsigned short* __restrict__ avb, const unsigned short* __restrict__ wot,
    const float* __restrict__ bo, float* __restrict__ out)
{
    __shared__ unsigned short As[64][72];
    __shared__ unsigned short Bs[64][72];
    const int row0 = blockIdx.x * 64;
    const int col0 = blockIdx.y * 64;
    const int tid = threadIdx.x, lane = tid & 63, w = tid >> 6;
    const int wm = (w & 1) * 32, wn = (w >> 1) * 32;
    const int frow = lane & 15, fk = (lane >> 4) * 8;

    f32x4 acc[2][2];
#pragma unroll
    for (int m = 0; m < 2; m++)
#pragma unroll
        for (int n = 0; n < 2; n++) acc[m][n] = (f32x4){0.f, 0.f, 0.f, 0.f};

    const int lr = tid >> 3;          // 0..31
    const int lc = (tid & 7) * 8;

    for (int k0 = 0; k0 < 512; k0 += 64) {
#pragma unroll
        for (int p = 0; p < 2; p++) {
            int r = lr + p * 32;
            *reinterpret_cast<short8*>(&As[r][lc]) =
                *reinterpret_cast<const short8*>(avb + (size_t)(row0 + r) * 512 + k0 + lc);
            *reinterpret_cast<short8*>(&Bs[r][lc]) =
                *reinterpret_cast<const short8*>(wot + (size_t)(col0 + r) * 512 + k0 + lc);
        }
        __syncthreads();
#pragma unroll
        for (int kk = 0; kk < 64; kk += 32) {
            short8 a[2], b[2];
#pragma unroll
            for (int m = 0; m < 2; m++)
                a[m] = *reinterpret_cast<const short8*>(&As[wm + m * 16 + frow][kk + fk]);
#pragma unroll
            for (int n = 0; n < 2; n++)
                b[n] = *reinterpret_cast<const short8*>(&Bs[wn + n * 16 + frow][kk + fk]);
#pragma unroll
            for (int m = 0; m < 2; m++)
#pragma unroll
                for (int n = 0; n < 2; n++)
                    acc[m][n] = __builtin_amdgcn_mfma_f32_16x16x32_bf16(
                        a[m], b[n], acc[m][n], 0, 0, 0);
        }
        __syncthreads();
    }

#pragma unroll
    for (int n = 0; n < 2; n++) {
        int col = col0 + wn + n * 16 + frow;
        float bv_ = bo[col];
#pragma unroll
        for (int m = 0; m < 2; m++) {
            int rbase = row0 + wm + m * 16 + (lane >> 4) * 4;
#pragma unroll
            for (int r = 0; r < 4; r++)
                out[(size_t)(rbase + r) * 512 + col] = acc[m][n][r] + bv_;
        }
    }
}

// ---------------------------------------------------------------------------
// K23 (fused chunk-KV + exclusive scan):
//   M'_c[d][h] = sum_{t in chunk c} V[t,d]*K[t,h];  Mb = exclusive prefix (bf16)
//   z_c[h] = sum_t K[t,h];                          zb = exclusive prefix (f32)
// grid (16, 16): x = (dblk<<2)|hblk tile of 16x16, y = bn. block 256 (4 waves).
// ---------------------------------------------------------------------------
__global__ __launch_bounds__(256) void chunk_kvscan_kernel(
    const unsigned short* __restrict__ pkT, const unsigned short* __restrict__ pvT,
    unsigned short* __restrict__ Mb, float* __restrict__ zb)
{
    __shared__ float waveTot[4][256];     // per-wave state totals
    __shared__ float zTot[4][16];         // per-wave z totals

    const int tile = blockIdx.x;
    const int bn   = blockIdx.y;
    const int d0   = (tile >> 2) * 16;
    const int h0   = (tile & 3) * 16;
    const int b = bn >> 3, n = bn & 7;
    const int tid = threadIdx.x, lane = tid & 63, w = tid >> 6;
    const int frow = lane & 15, grp = lane >> 4, fk = grp * 8;
    const bool do_z = (tile >> 2) == 0;

    const size_t vrow = (size_t)b * (512 * 2048) + (size_t)(n * 64 + d0 + frow) * 2048;
    const size_t krow = (size_t)b * (512 * 2048) + (size_t)(n * 64 + h0 + frow) * 2048;

    f32x4 run = (f32x4){0.f, 0.f, 0.f, 0.f};
    f32x4 loc[8];
    float runz = 0.f, locz[8];

#pragma unroll
    for (int c = 0; c < 8; c++) {
        int t0 = (w * 8 + c) * 64;
        loc[c] = run;
        locz[c] = runz;
        short8 a0 = *reinterpret_cast<const short8*>(pvT + vrow + t0 + fk);
        short8 a1 = *reinterpret_cast<const short8*>(pvT + vrow + t0 + 32 + fk);
        short8 b0 = *reinterpret_cast<const short8*>(pkT + krow + t0 + fk);
        short8 b1 = *reinterpret_cast<const short8*>(pkT + krow + t0 + 32 + fk);
        run = __builtin_amdgcn_mfma_f32_16x16x32_bf16(a0, b0, run, 0, 0, 0);
        run = __builtin_amdgcn_mfma_f32_16x16x32_bf16(a1, b1, run, 0, 0, 0);
        if (do_z) {
            float zp = 0.f;
#pragma unroll
            for (int j = 0; j < 8; j++) zp += bf2f((unsigned short)b0[j]) + bf2f((unsigned short)b1[j]);
            zp += __shfl_xor(zp, 16);
            zp += __shfl_xor(zp, 32);
            runz += zp;
        }
    }

    // publish wave totals
#pragma unroll
    for (int r = 0; r < 4; r++)
        waveTot[w][(grp * 4 + r) * 16 + frow] = run[r];
    if (do_z && lane < 16) zTot[w][frow] = runz;
    __syncthreads();

    // carry = sum of totals of preceding waves
    f32x4 carry = (f32x4){0.f, 0.f, 0.f, 0.f};
    float carryz = 0.f;
    for (int pw = 0; pw < w; pw++) {
#pragma unroll
        for (int r = 0; r < 4; r++)
            carry[r] += waveTot[pw][(grp * 4 + r) * 16 + frow];
        carryz += zTot[pw][frow];
    }

    // store exclusive prefixes (state as bf16)
#pragma unroll
    for (int c = 0; c < 8; c++) {
        size_t mbase = ((size_t)bn * NCH + (w * 8 + c)) * 4096;
#pragma unroll
        for (int r = 0; r < 4; r++)
            Mb[mbase + (size_t)(d0 + grp * 4 + r) * 64 + h0 + frow] = f2bf(carry[r] + loc[c][r]);
        if (do_z && lane < 16)
            zb[((size_t)bn * NCH + (w * 8 + c)) * 64 + h0 + frow] = carryz + locz[c];
    }
}

// ---------------------------------------------------------------------------
// K4 (MFMA): per-chunk attention.
//   A = tril(Q K^T); O = A V + Q Sp'; denom = qz_prev + rowsum(A) + eps
//   - Sp' fragments PRELOADED to registers before QK^T (latency hidden)
//   - no barrier between mask and PV (PV reads only own-wave Ab rows)
//   - scrambled result repacked via LDS -> coalesced short8 stores
// grid (NCH, NBN), block 256 (4 waves; wave w owns rows w*16..w*16+15)
// ---------------------------------------------------------------------------
__global__ __launch_bounds__(256) void chunk_attn_kernel(
    const unsigned short* __restrict__ pq, const unsigned short* __restrict__ pk,
    const unsigned short* __restrict__ pvT, const unsigned short* __restrict__ Mb,
    const float* __restrict__ zb, unsigned short* __restrict__ av)
{
    __shared__ unsigned short Qs[64][72], Ks[64][72], VT[64][72], Ab[64][72];
    __shared__ float zs[64], dqz4[64][4], dAS[64];
    unsigned short (* __restrict__ av8)[520] = (unsigned short(*)[520])Ab;  // 8x520x2 = 8320 <= 9216

    const int c = blockIdx.x, bn = blockIdx.y;
    const int b = bn >> 3, n = bn & 7;
    const int row0 = b * S_ + c * 64;
    const int col0 = n * 64;
    const int t0 = c * 64;
    const size_t vbase = (size_t)b * 512 * 2048;
    const size_t mbase = ((size_t)bn * NCH + c) * 4096;
    const int tid = threadIdx.x, lane = tid & 63, w = tid >> 6;

    // stage (all bf16, straight short8 copies)
#pragma unroll
    for (int p = 0; p < 2; p++) {
        int r  = (tid >> 3) + p * 32;
        int c8 = (tid & 7) * 8;
        *reinterpret_cast<short8*>(&Qs[r][c8]) =
            *reinterpret_cast<const short8*>(pq + (size_t)(row0 + r) * 512 + col0 + c8);
        *reinterpret_cast<short8*>(&Ks[r][c8]) =
            *reinterpret_cast<const short8*>(pk + (size_t)(row0 + r) * 512 + col0 + c8);
        *reinterpret_cast<short8*>(&VT[r][c8]) =
            *reinterpret_cast<const short8*>(pvT + vbase + (size_t)(col0 + r) * 2048 + t0 + c8);
    }
    if (tid < 64) zs[tid] = zb[((size_t)bn * NCH + c) * 64 + tid];
    __syncthreads();

    const int frow = lane & 15, grp = lane >> 4, fk = grp * 8;
    const int srow = w * 16;

    // PRELOAD Sp' fragments (issue early -> latency hides under QK^T)
    short8 sp[2][4];
#pragma unroll
    for (int ks = 0; ks < 2; ks++)
#pragma unroll
        for (int df = 0; df < 4; df++)
            sp[ks][df] = *reinterpret_cast<const short8*>(
                Mb + mbase + (size_t)(df * 16 + frow) * 64 + ks * 32 + fk);

    // QK^T
    f32x4 a1[4];
#pragma unroll
    for (int tf = 0; tf < 4; tf++) a1[tf] = (f32x4){0.f, 0.f, 0.f, 0.f};
#pragma unroll
    for (int ks = 0; ks < 2; ks++) {
        short8 qa = *reinterpret_cast<const short8*>(&Qs[srow + frow][ks * 32 + fk]);
#pragma unroll
        for (int tf = 0; tf < 4; tf++) {
            short8 kb = *reinterpret_cast<const short8*>(&Ks[tf * 16 + frow][ks * 32 + fk]);
            a1[tf] = __builtin_amdgcn_mfma_f32_16x16x32_bf16(qa, kb, a1[tf], 0, 0, 0);
        }
    }

    // mask + rowsum + Ab (own-wave rows only)
    float rs[4] = {0.f, 0.f, 0.f, 0.f};
#pragma unroll
    for (int tf = 0; tf < 4; tf++) {
        int t_ = tf * 16 + frow;
#pragma unroll
        for (int r = 0; r < 4; r++) {
            int s_ = srow + grp * 4 + r;
            float v = (t_ <= s_) ? a1[tf][r] : 0.f;
            rs[r] += v;
            Ab[s_][t_] = f2bf(v);
        }
    }
#pragma unroll
    for (int msk = 1; msk < 16; msk <<= 1)
#pragma unroll
        for (int r = 0; r < 4; r++) rs[r] += __shfl_xor(rs[r], msk);
    if (frow == 0) {
#pragma unroll
        for (int r = 0; r < 4; r++) dAS[srow + grp * 4 + r] = rs[r];
    }

    // q·z_prev, split across all 256 threads (16 MACs each)
    {
        int s = tid & 63, part = tid >> 6;
        float sdq = 0.f;
#pragma unroll
        for (int j = 0; j < 16; j++) {
            int h = part * 16 + j;
            sdq += bf2f(Qs[s][h]) * zs[h];
        }
        dqz4[s][part] = sdq;
    }

    // O = A V + Q Sp'  (no barrier: only own-wave Ab rows + staged Qs/VT + sp regs)
    f32x4 o[4];
#pragma unroll
    for (int df = 0; df < 4; df++) o[df] = (f32x4){0.f, 0.f, 0.f, 0.f};
#pragma unroll
    for (int ks = 0; ks < 2; ks++) {
        short8 aa = *reinterpret_cast<const short8*>(&Ab[srow + frow][ks * 32 + fk]);
        short8 qa = *reinterpret_cast<const short8*>(&Qs[srow + frow][ks * 32 + fk]);
#pragma unroll
        for (int df = 0; df < 4; df++) {
            short8 vb = *reinterpret_cast<const short8*>(&VT[df * 16 + frow][ks * 32 + fk]);
            o[df] = __builtin_amdgcn_mfma_f32_16x16x32_bf16(aa, vb, o[df], 0, 0, 0);
            o[df] = __builtin_amdgcn_mfma_f32_16x16x32_bf16(qa, sp[ks][df], o[df], 0, 0, 0);
        }
    }

    __syncthreads();   // dqz4/dAS complete; all waves done reading Ab

    // divide + scrambled repack into LDS (av8 overlays Ab)
    float inv[4];
#pragma unroll
    for (int r = 0; r < 4; r++) {
        int s_loc = srow + grp * 4 + r;
        float dq = dqz4[s_loc][0] + dqz4[s_loc][1] + dqz4[s_loc][2] + dqz4[s_loc][3];
        inv[r] = 1.f / (dq + dAS[s_loc] + EPS_);
    }
#pragma unroll
    for (int df = 0; df < 4; df++) {
        int d = df * 16 + frow;
#pragma unroll
        for (int r = 0; r < 4; r++) {
            int s_loc = srow + grp * 4 + r;
            av8[s_loc >> 3][(s_loc & 7) * 64 + d] = f2bf(o[df][r] * inv[r]);
        }
    }
    __syncthreads();

    // coalesced store: 8 complete rows of the out-proj input matrix (1KB each)
    const int orow0 = b * S_ + n * 256 + c * 8;
#pragma unroll
    for (int p = 0; p < 2; p++) {
        int idx = (p * 256 + tid) * 8;   // 0..4088
        int rr = idx >> 9;               // 0..7
        int cc = idx & 511;
        *reinterpret_cast<short8*>(av + (size_t)(orow0 + rr) * 512 + cc) =
            *reinterpret_cast<const short8*>(&av8[rr][cc]);
    }
}

// ---------------------------------------------------------------------------
extern "C" void kernel_launch(void* const* d_in, const int* in_sizes, int n_in,
                              void* d_out, int out_size, void* d_ws, size_t ws_size,
                              hipStream_t stream)
{
    const float* q_in = (const float*)d_in[0];
    const float* k_in = (const float*)d_in[1];
    const float* v_in = (const float*)d_in[2];
    const float* wq   = (const float*)d_in[3];
    const float* bq   = (const float*)d_in[4];
    const float* wk   = (const float*)d_in[5];
    const float* bk   = (const float*)d_in[6];
    const float* wv   = (const float*)d_in[7];
    const float* bv   = (const float*)d_in[8];
    const float* wo   = (const float*)d_in[9];
    const float* bo   = (const float*)d_in[10];
    float* out = (float*)d_out;

    const size_t PLANE = (size_t)BS_ * 512;   // 2,097,152 elems

    float* ws = (float*)d_ws;
    float* zbuf = ws;                         // 32768 f32
    unsigned short* u16 = (unsigned short*)(zbuf + 32768);
    unsigned short* Mb  = u16;                // PLANE bf16
    unsigned short* pq  = Mb  + PLANE;        // PLANE each
    unsigned short* pk  = pq  + PLANE;
    unsigned short* pkT = pk  + PLANE;
    unsigned short* pvT = pkT + PLANE;
    unsigned short* avb = pvT + PLANE;
    unsigned short* wqt = avb + PLANE;        // 262144 each
    unsigned short* wkt = wqt + 262144;
    unsigned short* wvt = wkt + 262144;
    unsigned short* wot = wvt + 262144;

    convert_wt_kernel<<<dim3(8, 8, 4), 256, 0, stream>>>(wq, wk, wv, wo, wqt, wkt, wvt, wot);
    qkv_proj_kernel<<<dim3(32, 4, 3), 256, 0, stream>>>(
        q_in, k_in, v_in, wqt, wkt, wvt, bq, bk, bv, pq, pk, pkT, pvT);
    chunk_kvscan_kernel<<<dim3(16, NBN), 256, 0, stream>>>(pkT, pvT, Mb, zbuf);
    chunk_attn_kernel<<<dim3(NCH, NBN), 256, 0, stream>>>(pq, pk, pvT, Mb, zbuf, avb);
    out_proj_kernel<<<dim3(64, 8), 256, 0, stream>>>(avb, wot, bo, out);
}